// Round 5
// baseline (1744.173 us; speedup 1.0000x reference)
//
#include <hip/hip_runtime.h>
#include <hip/hip_bf16.h>
#include <math.h>

// Problem constants (fixed by setup_inputs)
#define B_ 4
#define L_ 8192
#define M_ 4096
#define D_ 1024
#define CHUNK_ 16
#define NC_ 256         // M_/CHUNK_
#define EPS_ 1e-4f
#define SCOPE_AGENT __HIP_MEMORY_SCOPE_AGENT

// Round-to-nearest-even f32 -> bf16 -> f32 (values are finite here)
__device__ __forceinline__ float bf16rf(float x) {
  unsigned u = __float_as_uint(x);
  u += 0x7FFFu + ((u >> 16) & 1u);
  u &= 0xFFFF0000u;
  return __uint_as_float(u);
}

// boundary_mask may arrive as bool8 (fmt 0), int32 (fmt 1), or float32 (fmt 2)
__device__ __forceinline__ bool mask_at(const void* mb, int fmt, int i) {
  if (fmt == 0) return ((const unsigned char*)mb)[i] != 0;
  if (fmt == 1) return ((const int*)mb)[i] != 0;
  return ((const float*)mb)[i] != 0.0f;
}

// prep: one 1024-thread block per batch (round-3-verified structure).
__global__ void __launch_bounds__(1024)
k_prep(const float* __restrict__ bprob,
       const void* __restrict__ bmask,
       float4* __restrict__ scal,
       int* __restrict__ rowstart) {
  const int b = blockIdx.x;
  const int tid = threadIdx.x;  // 0..1023
  __shared__ int s_flags[2];
  __shared__ int s_psum[1024];
  __shared__ float s_p[M_];

  if (tid < 2) s_flags[tid] = 0;
  __syncthreads();
  {
    const unsigned* mw = (const unsigned*)bmask;
    unsigned f0 = 0, f1 = 0;
    for (int i = tid; i < 8192; i += 1024) {
      unsigned v = mw[i];
      f0 |= v & 0xFFu;    // byte0: nonzero for u8 and i32, zero for f32
      f1 |= v & 0xFF00u;  // byte1: nonzero only for u8 (45% density)
    }
    if (f1) s_flags[0] = 1;
    if (f0) s_flags[1] = 1;
  }
  __syncthreads();
  const int fmt = s_flags[0] ? 0 : (s_flags[1] ? 1 : 2);

  const int base_l = tid * (L_ / 1024);
  bool mloc[L_ / 1024];
  int cnt = 0;
#pragma unroll
  for (int j = 0; j < L_ / 1024; ++j) {
    mloc[j] = mask_at(bmask, fmt, b * L_ + base_l + j);
    cnt += mloc[j] ? 1 : 0;
  }
  s_psum[tid] = cnt;
  __syncthreads();
  for (int off = 1; off < 1024; off <<= 1) {
    int add = (tid >= off) ? s_psum[tid - off] : 0;
    __syncthreads();
    s_psum[tid] += add;
    __syncthreads();
  }
  const int nb = s_psum[1023];
  const int excl = s_psum[tid] - cnt;

  for (int r = tid; r <= M_; r += 1024) rowstart[b * (M_ + 1) + r] = L_;
  __syncthreads();

  int run = excl;
#pragma unroll
  for (int j = 0; j < L_ / 1024; ++j) {
    int l = base_l + j;
    bool mb = mloc[j];
    int pos = mb ? run : (nb + (l - run));
    run += mb ? 1 : 0;
    if (pos < M_) {
      s_p[pos] = bprob[((size_t)(b * L_ + l)) * 2 + 1];
      if (mb) rowstart[b * (M_ + 1) + pos] = l;
    }
  }
  __syncthreads();

#pragma unroll
  for (int i = 0; i < M_ / 1024; ++i) {
    int m = i * 1024 + tid;
    float p = s_p[m];
    p = fminf(fmaxf(p, EPS_), 1.0f - EPS_);
    float dtf = bf16rf(logf(1.0f / (1.0f - p)));
    float a = expf(-dtf);
    scal[b * M_ + m] = make_float4(a, dtf * p, 1.0f / dtf, 0.0f);
  }
}

// Single-pass scan with decoupled chunk-chain:
//  stage 1: local scan (h -> LDS, hidden read ONCE), publish partial + A_c,
//           release pflag.
//  stage 2: blocks (b==0, c<16) -- the 16 lowest linear IDs, dispatched first,
//           hence always schedulable before any waiter -- chain-scan one
//           quarter of D for one batch across all 256 chunks (groups of 16,
//           batched loads), rewrite stateP in place with inclusive values,
//           release iflag (+1 per worker; complete at 4).
//  stage 3: wait iflag[b][c-1] == 4, read carry, finalize, scatter.
// Every wait targets strictly lower linear block IDs => deadlock-free at any
// occupancy (in-order HW dispatch).
__global__ void __launch_bounds__(256, 4)
k_scan(const float* __restrict__ hidden,
       const float4* __restrict__ scal,
       const int* __restrict__ rowstart,
       float* __restrict__ stateP,   // [B][NC][D]
       float* __restrict__ Achunk,   // [B][NC]
       int* __restrict__ pflag,      // [B][NC]
       int* __restrict__ iflag,      // [B][NC]
       float* __restrict__ out) {
  const int c = blockIdx.x;   // chunk 0..NC_-1
  const int b = blockIdx.y;   // batch 0..B_-1
  const int tid = threadIdx.x;
  const int d4 = tid * 4;

  __shared__ float4 s_scal[CHUNK_];
  __shared__ float  s_cumA[CHUNK_];
  __shared__ int    s_rs[CHUNK_ + 1];
  __shared__ float4 s_h[CHUNK_ * 256];   // 16 KB: per-row states

  if (tid < CHUNK_)  s_scal[tid] = scal[b * M_ + c * CHUNK_ + tid];
  if (tid <= CHUNK_) s_rs[tid]   = rowstart[b * (M_ + 1) + c * CHUNK_ + tid];
  __syncthreads();
  const bool active = (s_rs[0] < L_);
  if (tid == 0) {
    float cp = 1.0f;
#pragma unroll
    for (int m = 0; m < CHUNK_; ++m) { cp *= s_scal[m].x; s_cumA[m] = cp; }
  }
  __syncthreads();

  // Stage 1: local scan with zero carry-in; h rows parked in LDS.
  float* sp = stateP + ((size_t)(b * NC_ + c)) * D_ + d4;
  {
    float hx = 0.f, hy = 0.f, hz = 0.f, hw = 0.f;
    if (active) {
      const float* __restrict__ hp =
          hidden + ((size_t)(b * M_ + c * CHUNK_)) * D_ + d4;
#pragma unroll
      for (int m = 0; m < CHUNK_; ++m) {
        const float4 s = s_scal[m];             // a, c=dt*p, 1/dt
        const float4 x = *(const float4*)(hp + (size_t)m * D_);
        hx = fmaf(s.x, hx, s.y * bf16rf(x.x * s.z));
        hy = fmaf(s.x, hy, s.y * bf16rf(x.y * s.z));
        hz = fmaf(s.x, hz, s.y * bf16rf(x.z * s.z));
        hw = fmaf(s.x, hw, s.y * bf16rf(x.w * s.z));
        s_h[m * 256 + tid] = make_float4(hx, hy, hz, hw);
      }
    }
    // publish partial (zeros if inactive so the chain never blocks)
    __hip_atomic_store(sp + 0, hx, __ATOMIC_RELAXED, SCOPE_AGENT);
    __hip_atomic_store(sp + 1, hy, __ATOMIC_RELAXED, SCOPE_AGENT);
    __hip_atomic_store(sp + 2, hz, __ATOMIC_RELAXED, SCOPE_AGENT);
    __hip_atomic_store(sp + 3, hw, __ATOMIC_RELAXED, SCOPE_AGENT);
    if (tid == 0)
      __hip_atomic_store(&Achunk[b * NC_ + c], active ? s_cumA[CHUNK_ - 1] : 0.f,
                         __ATOMIC_RELAXED, SCOPE_AGENT);
  }
  __syncthreads();  // drains vmcnt: all agent-scope stores globally visible
  if (tid == 0)
    __hip_atomic_store(&pflag[b * NC_ + c], 1, __ATOMIC_RELEASE, SCOPE_AGENT);

  // Stage 2: chain duty on the 16 first-dispatched blocks.
  if (b == 0 && c < 16) {
    const int bb = c >> 2;                 // batch served
    const int dd = (c & 3) * 256 + tid;    // dim served
    float S = 0.0f;
    for (int g = 0; g < NC_ / 16; ++g) {
      if (tid == 0) {
        for (int j = 0; j < 16; ++j)
          while (__hip_atomic_load(&pflag[bb * NC_ + g * 16 + j],
                                   __ATOMIC_ACQUIRE, SCOPE_AGENT) == 0)
            __builtin_amdgcn_s_sleep(2);
      }
      __syncthreads();
      float A[16], v[16];
#pragma unroll
      for (int j = 0; j < 16; ++j)
        A[j] = __hip_atomic_load(&Achunk[bb * NC_ + g * 16 + j],
                                 __ATOMIC_RELAXED, SCOPE_AGENT);
#pragma unroll
      for (int j = 0; j < 16; ++j)
        v[j] = __hip_atomic_load(&stateP[((size_t)(bb * NC_ + g * 16 + j)) * D_ + dd],
                                 __ATOMIC_RELAXED, SCOPE_AGENT);
#pragma unroll
      for (int j = 0; j < 16; ++j) { S = fmaf(A[j], S, v[j]); v[j] = S; }
#pragma unroll
      for (int j = 0; j < 16; ++j)
        __hip_atomic_store(&stateP[((size_t)(bb * NC_ + g * 16 + j)) * D_ + dd],
                           v[j], __ATOMIC_RELAXED, SCOPE_AGENT);
      __syncthreads();  // drain all waves' inclusive stores
      if (tid == 0)
#pragma unroll
        for (int j = 0; j < 16; ++j)
          __hip_atomic_fetch_add(&iflag[bb * NC_ + g * 16 + j], 1,
                                 __ATOMIC_RELEASE, SCOPE_AGENT);
    }
  }

  // Stage 3: finalize with true carry-in and scatter to output rows.
  if (active) {
    float4 ci = make_float4(0.f, 0.f, 0.f, 0.f);
    if (c > 0) {
      if (tid == 0)
        while (__hip_atomic_load(&iflag[b * NC_ + c - 1],
                                 __ATOMIC_ACQUIRE, SCOPE_AGENT) < 4)
          __builtin_amdgcn_s_sleep(2);
      __syncthreads();
      const float* ip = stateP + ((size_t)(b * NC_ + c - 1)) * D_ + d4;
      ci.x = __hip_atomic_load(ip + 0, __ATOMIC_RELAXED, SCOPE_AGENT);
      ci.y = __hip_atomic_load(ip + 1, __ATOMIC_RELAXED, SCOPE_AGENT);
      ci.z = __hip_atomic_load(ip + 2, __ATOMIC_RELAXED, SCOPE_AGENT);
      ci.w = __hip_atomic_load(ip + 3, __ATOMIC_RELAXED, SCOPE_AGENT);
    }
#pragma unroll
    for (int m = 0; m < CHUNK_; ++m) {
      const int r0 = s_rs[m], r1 = s_rs[m + 1];
      if (r1 > r0) {
        const float cA = s_cumA[m];
        const float4 hm = s_h[m * 256 + tid];
        float4 o;
        o.x = bf16rf(fmaf(ci.x, cA, hm.x));
        o.y = bf16rf(fmaf(ci.y, cA, hm.y));
        o.z = bf16rf(fmaf(ci.z, cA, hm.z));
        o.w = bf16rf(fmaf(ci.w, cA, hm.w));
        for (int l = r0; l < r1; ++l)
          *(float4*)(out + ((size_t)(b * L_ + l)) * D_ + d4) = o;
      }
    }
  }
}

extern "C" void kernel_launch(void* const* d_in, const int* in_sizes, int n_in,
                              void* d_out, int out_size, void* d_ws, size_t ws_size,
                              hipStream_t stream) {
  const float* hidden = (const float*)d_in[0];
  const float* bprob  = (const float*)d_in[1];
  const void*  bmask  = d_in[2];
  float* out = (float*)d_out;

  float4* scal    = (float4*)d_ws;                           // B*M float4
  float*  stateP  = (float*)(scal + B_ * M_);                // B*NC*D
  float*  Achunk  = stateP + (size_t)B_ * NC_ * D_;          // B*NC
  int*    rowstart = (int*)(Achunk + B_ * NC_);              // B*(M+1)
  int*    pflag   = rowstart + B_ * (M_ + 1);                // B*NC
  int*    iflag   = pflag + B_ * NC_;                        // B*NC

  hipMemsetAsync((void*)pflag, 0, 2 * B_ * NC_ * sizeof(int), stream);
  k_prep<<<dim3(B_), dim3(1024), 0, stream>>>(bprob, bmask, scal, rowstart);
  k_scan<<<dim3(NC_, B_), dim3(256), 0, stream>>>(hidden, scal, rowstart,
                                                  stateP, Achunk, pflag, iflag, out);
}

// Round 6
// 207.425 us; speedup vs baseline: 8.4087x; 8.4087x over previous
//
#include <hip/hip_runtime.h>
#include <hip/hip_bf16.h>
#include <hip/hip_cooperative_groups.h>
#include <math.h>

namespace cg = cooperative_groups;

// Problem constants (fixed by setup_inputs)
#define B_ 4
#define L_ 8192
#define M_ 4096
#define D_ 1024
#define CHUNK_ 32
#define NCC_ 128        // M_/CHUNK_
#define EPS_ 1e-4f

// Round-to-nearest-even f32 -> bf16 -> f32 (values are finite here)
__device__ __forceinline__ float bf16rf(float x) {
  unsigned u = __float_as_uint(x);
  u += 0x7FFFu + ((u >> 16) & 1u);
  u &= 0xFFFF0000u;
  return __uint_as_float(u);
}

// boundary_mask may arrive as bool8 (fmt 0), int32 (fmt 1), or float32 (fmt 2)
__device__ __forceinline__ bool mask_at(const void* mb, int fmt, int i) {
  if (fmt == 0) return ((const unsigned char*)mb)[i] != 0;
  if (fmt == 1) return ((const int*)mb)[i] != 0;
  return ((const float*)mb)[i] != 0.0f;
}

// prep: one 1024-thread block per batch (proven R3/R5 structure).
__global__ void __launch_bounds__(1024)
k_prep(const float* __restrict__ bprob,
       const void* __restrict__ bmask,
       float4* __restrict__ scal,
       int* __restrict__ rowstart) {
  const int b = blockIdx.x;
  const int tid = threadIdx.x;  // 0..1023
  __shared__ int s_flags[2];
  __shared__ int s_psum[1024];
  __shared__ float s_p[M_];

  if (tid < 2) s_flags[tid] = 0;
  __syncthreads();
  {
    const unsigned* mw = (const unsigned*)bmask;
    unsigned f0 = 0, f1 = 0;
    for (int i = tid; i < 8192; i += 1024) {
      unsigned v = mw[i];
      f0 |= v & 0xFFu;    // byte0: nonzero for u8 and i32, zero for f32
      f1 |= v & 0xFF00u;  // byte1: nonzero only for u8 (45% density)
    }
    if (f1) s_flags[0] = 1;
    if (f0) s_flags[1] = 1;
  }
  __syncthreads();
  const int fmt = s_flags[0] ? 0 : (s_flags[1] ? 1 : 2);

  const int base_l = tid * (L_ / 1024);
  bool mloc[L_ / 1024];
  int cnt = 0;
#pragma unroll
  for (int j = 0; j < L_ / 1024; ++j) {
    mloc[j] = mask_at(bmask, fmt, b * L_ + base_l + j);
    cnt += mloc[j] ? 1 : 0;
  }
  s_psum[tid] = cnt;
  __syncthreads();
  for (int off = 1; off < 1024; off <<= 1) {
    int add = (tid >= off) ? s_psum[tid - off] : 0;
    __syncthreads();
    s_psum[tid] += add;
    __syncthreads();
  }
  const int nb = s_psum[1023];
  const int excl = s_psum[tid] - cnt;

  for (int r = tid; r <= M_; r += 1024) rowstart[b * (M_ + 1) + r] = L_;
  __syncthreads();

  int run = excl;
#pragma unroll
  for (int j = 0; j < L_ / 1024; ++j) {
    int l = base_l + j;
    bool mb = mloc[j];
    int pos = mb ? run : (nb + (l - run));
    run += mb ? 1 : 0;
    if (pos < M_) {
      s_p[pos] = bprob[((size_t)(b * L_ + l)) * 2 + 1];
      if (mb) rowstart[b * (M_ + 1) + pos] = l;
    }
  }
  __syncthreads();

#pragma unroll
  for (int i = 0; i < M_ / 1024; ++i) {
    int m = i * 1024 + tid;
    float p = s_p[m];
    p = fminf(fmaxf(p, EPS_), 1.0f - EPS_);
    float dtf = bf16rf(logf(1.0f / (1.0f - p)));
    float a = expf(-dtf);
    scal[b * M_ + m] = make_float4(a, dtf * p, 1.0f / dtf, 0.0f);
  }
}

// Cooperative fused scan. 512 blocks x 256 threads = 2 blocks/CU at
// <=256 VGPR (__launch_bounds__(256,2)) -- 2x occupancy margin vs R4's
// failed exact-capacity config. hidden read ONCE; h[32] in registers.
__global__ void __launch_bounds__(256, 2)
k_fused(const float* __restrict__ hidden,
        const float4* __restrict__ scal,
        const int* __restrict__ rowstart,
        float* __restrict__ carry,    // [B][NCC][D]
        float* __restrict__ Achunk,   // [B][NCC]
        float* __restrict__ out) {
  const int c = blockIdx.x;   // chunk 0..NCC_-1
  const int b = blockIdx.y;   // batch 0..B_-1
  const int tid = threadIdx.x;
  const int d4 = tid * 4;

  __shared__ float4 s_scal[CHUNK_];
  __shared__ float  s_cumA[CHUNK_];
  __shared__ int    s_rs[CHUNK_ + 1];

  if (tid < CHUNK_)  s_scal[tid] = scal[b * M_ + c * CHUNK_ + tid];
  if (tid <= CHUNK_) s_rs[tid]   = rowstart[b * (M_ + 1) + c * CHUNK_ + tid];
  __syncthreads();
  if (tid == 0) {
    float cp = 1.0f;
#pragma unroll
    for (int m = 0; m < CHUNK_; ++m) { cp *= s_scal[m].x; s_cumA[m] = cp; }
    Achunk[b * NCC_ + c] = cp;
  }
  __syncthreads();
  const bool active = (s_rs[0] < L_);

  // Stage 1: local scan with zero carry-in; all h in registers.
  float4 h[CHUNK_];
  float hx = 0.f, hy = 0.f, hz = 0.f, hw = 0.f;
  if (active) {
    const float* __restrict__ hp =
        hidden + ((size_t)(b * M_ + c * CHUNK_)) * D_ + d4;
#pragma unroll
    for (int m = 0; m < CHUNK_; ++m) {
      const float4 s = s_scal[m];               // a, c=dt*p, 1/dt
      const float4 x = *(const float4*)(hp + (size_t)m * D_);
      hx = fmaf(s.x, hx, s.y * bf16rf(x.x * s.z));
      hy = fmaf(s.x, hy, s.y * bf16rf(x.y * s.z));
      hz = fmaf(s.x, hz, s.y * bf16rf(x.z * s.z));
      hw = fmaf(s.x, hw, s.y * bf16rf(x.w * s.z));
      h[m] = make_float4(hx, hy, hz, hw);
    }
  }
  *(float4*)(carry + ((size_t)(b * NCC_ + c)) * D_ + d4) =
      make_float4(hx, hy, hz, hw);

  cg::this_grid().sync();

  // Stage 2: chunk-chain scan on blocks (b==0, c<16): 16 blocks x 256 thr
  // = 4096 (batch,dim) chains, each 128 chunks in groups of 16 (batched
  // loads -> one latency per group).
  if (b == 0 && c < 16) {
    const int chain = c * 256 + tid;       // 0..4095
    const int bb = chain >> 10, dd = chain & 1023;
    const float* __restrict__ Ab = Achunk + bb * NCC_;
    float S = 0.0f;
    for (int g = 0; g < NCC_ / 16; ++g) {
      float v[16], A[16];
#pragma unroll
      for (int j = 0; j < 16; ++j)
        v[j] = carry[((size_t)(bb * NCC_ + g * 16 + j)) * D_ + dd];
#pragma unroll
      for (int j = 0; j < 16; ++j) A[j] = Ab[g * 16 + j];
#pragma unroll
      for (int j = 0; j < 16; ++j) { S = fmaf(A[j], S, v[j]); v[j] = S; }
#pragma unroll
      for (int j = 0; j < 16; ++j)
        carry[((size_t)(bb * NCC_ + g * 16 + j)) * D_ + dd] = v[j];
    }
  }

  cg::this_grid().sync();

  // Stage 3: finalize h_final(m) = h_local(m) + carry_in*cumA(m), scatter.
  if (active) {
    float4 ci = make_float4(0.f, 0.f, 0.f, 0.f);
    if (c > 0)
      ci = *(const float4*)(carry + ((size_t)(b * NCC_ + c - 1)) * D_ + d4);
#pragma unroll
    for (int m = 0; m < CHUNK_; ++m) {
      const int r0 = s_rs[m], r1 = s_rs[m + 1];
      if (r1 > r0) {
        const float cA = s_cumA[m];
        float4 o;
        o.x = bf16rf(fmaf(ci.x, cA, h[m].x));
        o.y = bf16rf(fmaf(ci.y, cA, h[m].y));
        o.z = bf16rf(fmaf(ci.z, cA, h[m].z));
        o.w = bf16rf(fmaf(ci.w, cA, h[m].w));
        for (int l = r0; l < r1; ++l)
          *(float4*)(out + ((size_t)(b * L_ + l)) * D_ + d4) = o;
      }
    }
  }
}

// ---------- Fallback path (R3-proven 3-pass structure, CHUNK=32) ----------
__global__ void k_scanA(const float* __restrict__ hidden,
                        const float4* __restrict__ scal,
                        const int* __restrict__ rowstart,
                        float* __restrict__ carry,
                        float* __restrict__ Achunk) {
  const int c = blockIdx.x, b = blockIdx.y;
  const int tid = threadIdx.x;
  __shared__ float4 s_scal[CHUNK_];
  if (tid < CHUNK_) s_scal[tid] = scal[b * M_ + c * CHUNK_ + tid];
  __syncthreads();
  if (tid == 0) {
    float cp = 1.0f;
#pragma unroll
    for (int m = 0; m < CHUNK_; ++m) cp *= s_scal[m].x;
    Achunk[b * NCC_ + c] = cp;
  }
  const int d4 = tid * 4;
  float hx = 0.f, hy = 0.f, hz = 0.f, hw = 0.f;
  if (rowstart[b * (M_ + 1) + c * CHUNK_] < L_) {
    const float* __restrict__ hp =
        hidden + ((size_t)(b * M_ + c * CHUNK_)) * D_ + d4;
#pragma unroll
    for (int m = 0; m < CHUNK_; ++m) {
      const float4 s = s_scal[m];
      const float4 x = *(const float4*)(hp + (size_t)m * D_);
      hx = fmaf(s.x, hx, s.y * bf16rf(x.x * s.z));
      hy = fmaf(s.x, hy, s.y * bf16rf(x.y * s.z));
      hz = fmaf(s.x, hz, s.y * bf16rf(x.z * s.z));
      hw = fmaf(s.x, hw, s.y * bf16rf(x.w * s.z));
    }
  }
  *(float4*)(carry + ((size_t)(b * NCC_ + c)) * D_ + d4) =
      make_float4(hx, hy, hz, hw);
}

__global__ void __launch_bounds__(256)
k_scanB(float* __restrict__ carry, const float* __restrict__ Achunk) {
  const int chain = blockIdx.x * 256 + threadIdx.x;  // 0..4095
  const int bb = chain >> 10, dd = chain & 1023;
  const float* __restrict__ Ab = Achunk + bb * NCC_;
  float S = 0.0f;
  for (int g = 0; g < NCC_ / 16; ++g) {
    float v[16], A[16];
#pragma unroll
    for (int j = 0; j < 16; ++j)
      v[j] = carry[((size_t)(bb * NCC_ + g * 16 + j)) * D_ + dd];
#pragma unroll
    for (int j = 0; j < 16; ++j) A[j] = Ab[g * 16 + j];
#pragma unroll
    for (int j = 0; j < 16; ++j) { S = fmaf(A[j], S, v[j]); v[j] = S; }
#pragma unroll
    for (int j = 0; j < 16; ++j)
      carry[((size_t)(bb * NCC_ + g * 16 + j)) * D_ + dd] = v[j];
  }
}

__global__ void k_scanC(const float* __restrict__ hidden,
                        const float4* __restrict__ scal,
                        const int* __restrict__ rowstart,
                        const float* __restrict__ carry,
                        float* __restrict__ out) {
  const int c = blockIdx.x, b = blockIdx.y;
  const int tid = threadIdx.x;
  __shared__ float4 s_scal[CHUNK_];
  __shared__ int    s_rs[CHUNK_ + 1];
  if (tid < CHUNK_)  s_scal[tid] = scal[b * M_ + c * CHUNK_ + tid];
  if (tid <= CHUNK_) s_rs[tid]   = rowstart[b * (M_ + 1) + c * CHUNK_ + tid];
  __syncthreads();
  if (s_rs[0] >= L_) return;
  const int d4 = tid * 4;
  float hx = 0.f, hy = 0.f, hz = 0.f, hw = 0.f;
  if (c > 0) {
    const float4 ci = *(const float4*)(carry + ((size_t)(b * NCC_ + c - 1)) * D_ + d4);
    hx = ci.x; hy = ci.y; hz = ci.z; hw = ci.w;
  }
  const float* __restrict__ hp =
      hidden + ((size_t)(b * M_ + c * CHUNK_)) * D_ + d4;
#pragma unroll
  for (int m = 0; m < CHUNK_; ++m) {
    const float4 s = s_scal[m];
    const float4 x = *(const float4*)(hp + (size_t)m * D_);
    hx = fmaf(s.x, hx, s.y * bf16rf(x.x * s.z));
    hy = fmaf(s.x, hy, s.y * bf16rf(x.y * s.z));
    hz = fmaf(s.x, hz, s.y * bf16rf(x.z * s.z));
    hw = fmaf(s.x, hw, s.y * bf16rf(x.w * s.z));
    const int r0 = s_rs[m], r1 = s_rs[m + 1];
    if (r1 > r0) {
      float4 o = make_float4(bf16rf(hx), bf16rf(hy), bf16rf(hz), bf16rf(hw));
      for (int l = r0; l < r1; ++l)
        *(float4*)(out + ((size_t)(b * L_ + l)) * D_ + d4) = o;
    }
  }
}

extern "C" void kernel_launch(void* const* d_in, const int* in_sizes, int n_in,
                              void* d_out, int out_size, void* d_ws, size_t ws_size,
                              hipStream_t stream) {
  const float* hidden = (const float*)d_in[0];
  const float* bprob  = (const float*)d_in[1];
  const void*  bmask  = d_in[2];
  float* out = (float*)d_out;

  float4* scal    = (float4*)d_ws;                           // B*M float4
  float*  carry   = (float*)(scal + B_ * M_);                // B*NCC*D
  float*  Achunk  = carry + (size_t)B_ * NCC_ * D_;          // B*NCC
  int*    rowstart = (int*)(Achunk + B_ * NCC_);             // B*(M+1)

  k_prep<<<dim3(B_), dim3(1024), 0, stream>>>(bprob, bmask, scal, rowstart);

  void* args[] = {(void*)&hidden, (void*)&scal, (void*)&rowstart,
                  (void*)&carry, (void*)&Achunk, (void*)&out};
  hipError_t e = hipLaunchCooperativeKernel((void*)k_fused, dim3(NCC_, B_),
                                            dim3(256), args, 0, stream);
  if (e != hipSuccess) {
    // Fallback: proven 3-pass structure (reads hidden twice).
    k_scanA<<<dim3(NCC_, B_), dim3(256), 0, stream>>>(hidden, scal, rowstart,
                                                      carry, Achunk);
    k_scanB<<<dim3(16), dim3(256), 0, stream>>>(carry, Achunk);
    k_scanC<<<dim3(NCC_, B_), dim3(256), 0, stream>>>(hidden, scal, rowstart,
                                                      carry, out);
  }
}

// Round 7
// 90.176 us; speedup vs baseline: 19.3418x; 2.3002x over previous
//
#include <hip/hip_runtime.h>
#include <hip/hip_bf16.h>
#include <math.h>

// Problem constants (fixed by setup_inputs)
#define B_ 4
#define L_ 8192
#define M_ 4096
#define D_ 1024
#define CHUNK_ 32
#define NCC_ 128        // M_/CHUNK_
#define EPS_ 1e-4f

// Round-to-nearest-even f32 -> bf16 -> f32 (values are finite here)
__device__ __forceinline__ float bf16rf(float x) {
  unsigned u = __float_as_uint(x);
  u += 0x7FFFu + ((u >> 16) & 1u);
  u &= 0xFFFF0000u;
  return __uint_as_float(u);
}

// boundary_mask may arrive as bool8 (fmt 0), int32 (fmt 1), or float32 (fmt 2)
__device__ __forceinline__ bool mask_at(const void* mb, int fmt, int i) {
  if (fmt == 0) return ((const unsigned char*)mb)[i] != 0;
  if (fmt == 1) return ((const int*)mb)[i] != 0;
  return ((const float*)mb)[i] != 0.0f;
}

// prep: one 1024-thread block per batch (proven R3/R5/R6 structure).
__global__ void __launch_bounds__(1024)
k_prep(const float* __restrict__ bprob,
       const void* __restrict__ bmask,
       float4* __restrict__ scal,
       int* __restrict__ rowstart) {
  const int b = blockIdx.x;
  const int tid = threadIdx.x;  // 0..1023
  __shared__ int s_flags[2];
  __shared__ int s_psum[1024];
  __shared__ float s_p[M_];

  if (tid < 2) s_flags[tid] = 0;
  __syncthreads();
  {
    const unsigned* mw = (const unsigned*)bmask;
    unsigned f0 = 0, f1 = 0;
    for (int i = tid; i < 8192; i += 1024) {
      unsigned v = mw[i];
      f0 |= v & 0xFFu;    // byte0: nonzero for u8 and i32, zero for f32
      f1 |= v & 0xFF00u;  // byte1: nonzero only for u8 (45% density)
    }
    if (f1) s_flags[0] = 1;
    if (f0) s_flags[1] = 1;
  }
  __syncthreads();
  const int fmt = s_flags[0] ? 0 : (s_flags[1] ? 1 : 2);

  const int base_l = tid * (L_ / 1024);
  bool mloc[L_ / 1024];
  int cnt = 0;
#pragma unroll
  for (int j = 0; j < L_ / 1024; ++j) {
    mloc[j] = mask_at(bmask, fmt, b * L_ + base_l + j);
    cnt += mloc[j] ? 1 : 0;
  }
  s_psum[tid] = cnt;
  __syncthreads();
  for (int off = 1; off < 1024; off <<= 1) {
    int add = (tid >= off) ? s_psum[tid - off] : 0;
    __syncthreads();
    s_psum[tid] += add;
    __syncthreads();
  }
  const int nb = s_psum[1023];
  const int excl = s_psum[tid] - cnt;

  for (int r = tid; r <= M_; r += 1024) rowstart[b * (M_ + 1) + r] = L_;
  __syncthreads();

  int run = excl;
#pragma unroll
  for (int j = 0; j < L_ / 1024; ++j) {
    int l = base_l + j;
    bool mb = mloc[j];
    int pos = mb ? run : (nb + (l - run));
    run += mb ? 1 : 0;
    if (pos < M_) {
      s_p[pos] = bprob[((size_t)(b * L_ + l)) * 2 + 1];
      if (mb) rowstart[b * (M_ + 1) + pos] = l;
    }
  }
  __syncthreads();

#pragma unroll
  for (int i = 0; i < M_ / 1024; ++i) {
    int m = i * 1024 + tid;
    float p = s_p[m];
    p = fminf(fmaxf(p, EPS_), 1.0f - EPS_);
    float dtf = bf16rf(logf(1.0f / (1.0f - p)));
    float a = expf(-dtf);
    scal[b * M_ + m] = make_float4(a, dtf * p, 1.0f / dtf, 0.0f);
  }
}

// Pass A: per-(batch,chunk) local scan with zero carry-in; emit chunk-end
// partial state (carry) and chunk decay product (Achunk). Streaming, no
// per-thread arrays -> no spill risk.
__global__ void k_scanA(const float* __restrict__ hidden,
                        const float4* __restrict__ scal,
                        const int* __restrict__ rowstart,
                        float* __restrict__ carry,     // [B][NCC][D]
                        float* __restrict__ Achunk) {  // [B][NCC]
  const int c = blockIdx.x, b = blockIdx.y;
  const int tid = threadIdx.x;
  if (rowstart[b * (M_ + 1) + c * CHUNK_] >= L_) return;  // inactive chunk
  __shared__ float4 s_scal[CHUNK_];
  if (tid < CHUNK_) s_scal[tid] = scal[b * M_ + c * CHUNK_ + tid];
  __syncthreads();
  if (tid == 0) {
    float cp = 1.0f;
#pragma unroll
    for (int m = 0; m < CHUNK_; ++m) cp *= s_scal[m].x;
    Achunk[b * NCC_ + c] = cp;
  }
  const int d4 = tid * 4;
  const float* __restrict__ hp =
      hidden + ((size_t)(b * M_ + c * CHUNK_)) * D_ + d4;
  float hx = 0.f, hy = 0.f, hz = 0.f, hw = 0.f;
#pragma unroll
  for (int m = 0; m < CHUNK_; ++m) {
    const float4 s = s_scal[m];                 // a, c=dt*p, 1/dt
    const float4 x = *(const float4*)(hp + (size_t)m * D_);
    hx = fmaf(s.x, hx, s.y * bf16rf(x.x * s.z));
    hy = fmaf(s.x, hy, s.y * bf16rf(x.y * s.z));
    hz = fmaf(s.x, hz, s.y * bf16rf(x.z * s.z));
    hw = fmaf(s.x, hw, s.y * bf16rf(x.w * s.z));
  }
  *(float4*)(carry + ((size_t)(b * NCC_ + c)) * D_ + d4) =
      make_float4(hx, hy, hz, hw);
}

// Pass C: each block derives its own exclusive carry-in as a weighted sum
// over predecessor chunk partials (w_j = prod_{k=j+1}^{c-1} A_k, built in
// LDS). carry is 2 MB total -> these re-reads are L2/L3 hits, not HBM.
// Then local rescan of hidden with true carry-in, fused token scatter.
__global__ void k_scanC(const float* __restrict__ hidden,
                        const float4* __restrict__ scal,
                        const int* __restrict__ rowstart,
                        const float* __restrict__ carry,
                        const float* __restrict__ Achunk,
                        float* __restrict__ out) {
  const int c = blockIdx.x, b = blockIdx.y;
  const int tid = threadIdx.x;
  __shared__ float4 s_scal[CHUNK_];
  __shared__ int    s_rs[CHUNK_ + 1];
  __shared__ float  s_w[NCC_];
  if (tid < CHUNK_)  s_scal[tid] = scal[b * M_ + c * CHUNK_ + tid];
  if (tid <= CHUNK_) s_rs[tid]   = rowstart[b * (M_ + 1) + c * CHUNK_ + tid];
  if (tid < c)       s_w[tid]    = Achunk[b * NCC_ + tid];  // stash A_j
  __syncthreads();
  if (s_rs[0] >= L_) return;                    // inactive chunk
  if (tid == 0 && c > 0) {
    // In place: s_w[j] = prod_{k=j+1}^{c-1} A_k (suffix products, desc j)
    float run = 1.0f;
    for (int j = c - 1; j >= 0; --j) {
      float Aj = s_w[j];
      s_w[j] = run;
      run *= Aj;
    }
  }
  __syncthreads();

  const int d4 = tid * 4;
  float hx = 0.f, hy = 0.f, hz = 0.f, hw = 0.f;
  // Exclusive carry-in: sum_j w_j * partial_j  (j ascending, L2-resident)
#pragma unroll 4
  for (int j = 0; j < c; ++j) {
    const float wj = s_w[j];
    const float4 pj =
        *(const float4*)(carry + ((size_t)(b * NCC_ + j)) * D_ + d4);
    hx = fmaf(wj, pj.x, hx);
    hy = fmaf(wj, pj.y, hy);
    hz = fmaf(wj, pj.z, hz);
    hw = fmaf(wj, pj.w, hw);
  }

  // Local rescan with true carry-in; scatter each boundary row range.
  const float* __restrict__ hp =
      hidden + ((size_t)(b * M_ + c * CHUNK_)) * D_ + d4;
#pragma unroll
  for (int m = 0; m < CHUNK_; ++m) {
    const float4 s = s_scal[m];
    const float4 x = *(const float4*)(hp + (size_t)m * D_);
    hx = fmaf(s.x, hx, s.y * bf16rf(x.x * s.z));
    hy = fmaf(s.x, hy, s.y * bf16rf(x.y * s.z));
    hz = fmaf(s.x, hz, s.y * bf16rf(x.z * s.z));
    hw = fmaf(s.x, hw, s.y * bf16rf(x.w * s.z));
    const int r0 = s_rs[m], r1 = s_rs[m + 1];
    if (r1 > r0) {
      float4 o = make_float4(bf16rf(hx), bf16rf(hy), bf16rf(hz), bf16rf(hw));
      for (int l = r0; l < r1; ++l)
        *(float4*)(out + ((size_t)(b * L_ + l)) * D_ + d4) = o;
    }
  }
}

extern "C" void kernel_launch(void* const* d_in, const int* in_sizes, int n_in,
                              void* d_out, int out_size, void* d_ws, size_t ws_size,
                              hipStream_t stream) {
  const float* hidden = (const float*)d_in[0];
  const float* bprob  = (const float*)d_in[1];
  const void*  bmask  = d_in[2];
  float* out = (float*)d_out;

  float4* scal    = (float4*)d_ws;                           // B*M float4
  float*  carry   = (float*)(scal + B_ * M_);                // B*NCC*D
  float*  Achunk  = carry + (size_t)B_ * NCC_ * D_;          // B*NCC
  int*    rowstart = (int*)(Achunk + B_ * NCC_);             // B*(M+1)

  k_prep<<<dim3(B_), dim3(1024), 0, stream>>>(bprob, bmask, scal, rowstart);
  k_scanA<<<dim3(NCC_, B_), dim3(256), 0, stream>>>(hidden, scal, rowstart,
                                                    carry, Achunk);
  k_scanC<<<dim3(NCC_, B_), dim3(256), 0, stream>>>(hidden, scal, rowstart,
                                                    carry, Achunk, out);
}

// Round 8
// 87.123 us; speedup vs baseline: 20.0196x; 1.0350x over previous
//
#include <hip/hip_runtime.h>
#include <hip/hip_bf16.h>
#include <math.h>

// Problem constants (fixed by setup_inputs)
#define B_ 4
#define L_ 8192
#define M_ 4096
#define D_ 1024
#define CHUNK_ 32
#define NCC_ 128        // M_/CHUNK_
#define EPS_ 1e-4f

// Round-to-nearest-even f32 -> bf16 -> f32 (values are finite here)
__device__ __forceinline__ float bf16rf(float x) {
  unsigned u = __float_as_uint(x);
  u += 0x7FFFu + ((u >> 16) & 1u);
  u &= 0xFFFF0000u;
  return __uint_as_float(u);
}

// boundary_mask may arrive as bool8 (fmt 0), int32 (fmt 1), or float32 (fmt 2)
__device__ __forceinline__ bool mask_at(const void* mb, int fmt, int i) {
  if (fmt == 0) return ((const unsigned char*)mb)[i] != 0;
  if (fmt == 1) return ((const int*)mb)[i] != 0;
  return ((const float*)mb)[i] != 0.0f;
}

// prep: one 1024-thread block per batch. Wave-level prefix scan (2 barriers
// on the scan path instead of Hillis-Steele's 20).
__global__ void __launch_bounds__(1024)
k_prep(const float* __restrict__ bprob,
       const void* __restrict__ bmask,
       float4* __restrict__ scal,
       int* __restrict__ rowstart) {
  const int b = blockIdx.x;
  const int tid = threadIdx.x;  // 0..1023
  const int lane = tid & 63, wid = tid >> 6;
  __shared__ int s_flags[2];
  __shared__ int s_wsum[17];
  __shared__ float s_p[M_];

  if (tid < 2) s_flags[tid] = 0;
  __syncthreads();
  {
    const unsigned* mw = (const unsigned*)bmask;
    unsigned f0 = 0, f1 = 0;
    for (int i = tid; i < 8192; i += 1024) {
      unsigned v = mw[i];
      f0 |= v & 0xFFu;    // byte0: nonzero for u8 and i32, zero for f32
      f1 |= v & 0xFF00u;  // byte1: nonzero only for u8 (45% density)
    }
    if (f1) s_flags[0] = 1;
    if (f0) s_flags[1] = 1;
  }
  __syncthreads();
  const int fmt = s_flags[0] ? 0 : (s_flags[1] ? 1 : 2);

  // 8 contiguous tokens per thread
  const int base_l = tid * (L_ / 1024);
  bool mloc[L_ / 1024];
  int cnt = 0;
#pragma unroll
  for (int j = 0; j < L_ / 1024; ++j) {
    mloc[j] = mask_at(bmask, fmt, b * L_ + base_l + j);
    cnt += mloc[j] ? 1 : 0;
  }
  // wave-level inclusive scan of cnt (wave = 64 lanes on gfx950)
  int incl = cnt;
#pragma unroll
  for (int off = 1; off < 64; off <<= 1) {
    int t = __shfl_up(incl, off);
    if (lane >= off) incl += t;
  }
  if (lane == 63) s_wsum[wid] = incl;
  __syncthreads();
  if (tid == 0) {
    int acc = 0;
#pragma unroll
    for (int w = 0; w < 16; ++w) { int t = s_wsum[w]; s_wsum[w] = acc; acc += t; }
    s_wsum[16] = acc;
  }
  // rowstart defaults while waiting (independent of scan)
  for (int r = tid; r <= M_; r += 1024) rowstart[b * (M_ + 1) + r] = L_;
  __syncthreads();
  const int excl = s_wsum[wid] + incl - cnt;  // boundaries before this thread
  const int nb = s_wsum[16];                  // total boundaries in batch b

  int run = excl;
#pragma unroll
  for (int j = 0; j < L_ / 1024; ++j) {
    int l = base_l + j;
    bool mb = mloc[j];
    int pos = mb ? run : (nb + (l - run));
    run += mb ? 1 : 0;
    if (pos < M_) {
      s_p[pos] = bprob[((size_t)(b * L_ + l)) * 2 + 1];
      if (mb) rowstart[b * (M_ + 1) + pos] = l;
    }
  }
  __syncthreads();

#pragma unroll
  for (int i = 0; i < M_ / 1024; ++i) {
    int m = i * 1024 + tid;
    float p = s_p[m];
    p = fminf(fmaxf(p, EPS_), 1.0f - EPS_);
    float dtf = bf16rf(logf(1.0f / (1.0f - p)));
    float a = expf(-dtf);
    scal[b * M_ + m] = make_float4(a, dtf * p, 1.0f / dtf, 0.0f);
  }
}

// Pass A: per-(batch,chunk) local scan with zero carry-in; emit chunk-end
// partial state (carry) and chunk decay product (Achunk).
__global__ void __launch_bounds__(256)
k_scanA(const float* __restrict__ hidden,
        const float4* __restrict__ scal,
        const int* __restrict__ rowstart,
        float* __restrict__ carry,     // [B][NCC][D]
        float* __restrict__ Achunk) {  // [B][NCC]
  const int c = blockIdx.x, b = blockIdx.y;
  const int tid = threadIdx.x;
  if (rowstart[b * (M_ + 1) + c * CHUNK_] >= L_) return;  // inactive chunk
  __shared__ float4 s_scal[CHUNK_];
  if (tid < CHUNK_) s_scal[tid] = scal[b * M_ + c * CHUNK_ + tid];
  __syncthreads();
  if (tid == 0) {
    float cp = 1.0f;
#pragma unroll
    for (int m = 0; m < CHUNK_; ++m) cp *= s_scal[m].x;
    Achunk[b * NCC_ + c] = cp;
  }
  const int d4 = tid * 4;
  const float* __restrict__ hp =
      hidden + ((size_t)(b * M_ + c * CHUNK_)) * D_ + d4;
  float hx = 0.f, hy = 0.f, hz = 0.f, hw = 0.f;
#pragma unroll
  for (int m = 0; m < CHUNK_; ++m) {
    const float4 s = s_scal[m];                 // a, c=dt*p, 1/dt
    const float4 x = *(const float4*)(hp + (size_t)m * D_);
    hx = fmaf(s.x, hx, s.y * bf16rf(x.x * s.z));
    hy = fmaf(s.x, hy, s.y * bf16rf(x.y * s.z));
    hz = fmaf(s.x, hz, s.y * bf16rf(x.z * s.z));
    hw = fmaf(s.x, hw, s.y * bf16rf(x.w * s.z));
  }
  *(float4*)(carry + ((size_t)(b * NCC_ + c)) * D_ + d4) =
      make_float4(hx, hy, hz, hw);
}

// Pass B: in-place inclusive scan across chunks. 4096 chains (b,d); each
// thread batches 16 independent loads -> one latency per 16 chunks.
__global__ void __launch_bounds__(64)
k_scanB(float* __restrict__ carry, const float* __restrict__ Achunk) {
  const int chain = blockIdx.x * 64 + threadIdx.x;  // 0..4095
  const int bb = chain >> 10, dd = chain & 1023;
  const float* __restrict__ Ab = Achunk + bb * NCC_;
  float S = 0.0f;
  for (int g = 0; g < NCC_ / 16; ++g) {
    float v[16], A[16];
#pragma unroll
    for (int j = 0; j < 16; ++j)
      v[j] = carry[((size_t)(bb * NCC_ + g * 16 + j)) * D_ + dd];
#pragma unroll
    for (int j = 0; j < 16; ++j) A[j] = Ab[g * 16 + j];
#pragma unroll
    for (int j = 0; j < 16; ++j) { S = fmaf(A[j], S, v[j]); v[j] = S; }
#pragma unroll
    for (int j = 0; j < 16; ++j)
      carry[((size_t)(bb * NCC_ + g * 16 + j)) * D_ + dd] = v[j];
  }
}

// Pass C: read single exclusive-carry vector, local rescan of hidden with
// true carry-in, fused token scatter.
__global__ void __launch_bounds__(256)
k_scanC(const float* __restrict__ hidden,
        const float4* __restrict__ scal,
        const int* __restrict__ rowstart,
        const float* __restrict__ carry,
        float* __restrict__ out) {
  const int c = blockIdx.x, b = blockIdx.y;
  const int tid = threadIdx.x;
  __shared__ float4 s_scal[CHUNK_];
  __shared__ int    s_rs[CHUNK_ + 1];
  if (tid < CHUNK_)  s_scal[tid] = scal[b * M_ + c * CHUNK_ + tid];
  if (tid <= CHUNK_) s_rs[tid]   = rowstart[b * (M_ + 1) + c * CHUNK_ + tid];
  __syncthreads();
  if (s_rs[0] >= L_) return;                    // inactive chunk
  const int d4 = tid * 4;
  float hx = 0.f, hy = 0.f, hz = 0.f, hw = 0.f;
  if (c > 0) {
    const float4 ci =
        *(const float4*)(carry + ((size_t)(b * NCC_ + c - 1)) * D_ + d4);
    hx = ci.x; hy = ci.y; hz = ci.z; hw = ci.w;
  }
  const float* __restrict__ hp =
      hidden + ((size_t)(b * M_ + c * CHUNK_)) * D_ + d4;
#pragma unroll
  for (int m = 0; m < CHUNK_; ++m) {
    const float4 s = s_scal[m];
    const float4 x = *(const float4*)(hp + (size_t)m * D_);
    hx = fmaf(s.x, hx, s.y * bf16rf(x.x * s.z));
    hy = fmaf(s.x, hy, s.y * bf16rf(x.y * s.z));
    hz = fmaf(s.x, hz, s.y * bf16rf(x.z * s.z));
    hw = fmaf(s.x, hw, s.y * bf16rf(x.w * s.z));
    const int r0 = s_rs[m], r1 = s_rs[m + 1];
    if (r1 > r0) {
      float4 o = make_float4(bf16rf(hx), bf16rf(hy), bf16rf(hz), bf16rf(hw));
      for (int l = r0; l < r1; ++l)
        *(float4*)(out + ((size_t)(b * L_ + l)) * D_ + d4) = o;
    }
  }
}

extern "C" void kernel_launch(void* const* d_in, const int* in_sizes, int n_in,
                              void* d_out, int out_size, void* d_ws, size_t ws_size,
                              hipStream_t stream) {
  const float* hidden = (const float*)d_in[0];
  const float* bprob  = (const float*)d_in[1];
  const void*  bmask  = d_in[2];
  float* out = (float*)d_out;

  float4* scal    = (float4*)d_ws;                           // B*M float4
  float*  carry   = (float*)(scal + B_ * M_);                // B*NCC*D
  float*  Achunk  = carry + (size_t)B_ * NCC_ * D_;          // B*NCC
  int*    rowstart = (int*)(Achunk + B_ * NCC_);             // B*(M+1)

  k_prep<<<dim3(B_), dim3(1024), 0, stream>>>(bprob, bmask, scal, rowstart);
  k_scanA<<<dim3(NCC_, B_), dim3(256), 0, stream>>>(hidden, scal, rowstart,
                                                    carry, Achunk);
  k_scanB<<<dim3(64), dim3(64), 0, stream>>>(carry, Achunk);
  k_scanC<<<dim3(NCC_, B_), dim3(256), 0, stream>>>(hidden, scal, rowstart,
                                                    carry, out);
}